// Round 8
// baseline (168.340 us; speedup 1.0000x reference)
//
#include <hip/hip_runtime.h>

#define NN 50000
#define NE 1600000
#define DIM 256
#define OUTD 64
#define ALPHA 0.2f

#define BSH 6                  // bucket = src >> 6 (64 nodes/bucket)
#define NB ((NN + 63) >> 6)    // 782 buckets
#define CAP 3072               // per-bucket capacity (mean 2048, sigma ~45)
#define P1 128                 // binning blocks (16-edge = 64B chunks, exclusive lines)
#define EPB (NE / P1)          // 12500 edges per block (div by 4)

#define GEMM_BLOCKS ((NN + 63) / 64)  // 782 (64 rows/block = 16 rows x 4 waves)
#define WSTRIDE 264            // Wl LDS row stride in u16 (256 + 8 pad)

typedef unsigned short u16;
typedef unsigned int u32;
typedef __attribute__((ext_vector_type(8))) short short8;   // 8 bf16 MFMA frag
typedef __attribute__((ext_vector_type(4))) float floatx4;  // MFMA accum

__device__ __forceinline__ u16 f2bf(float f) {
  u32 b = __float_as_uint(f);
  b += 0x7FFFu + ((b >> 16) & 1u);  // RNE
  return (u16)(b >> 16);
}
__device__ __forceinline__ float bflo(u32 u) { return __uint_as_float(u << 16); }
__device__ __forceinline__ float bfhi(u32 u) { return __uint_as_float(u & 0xFFFF0000u); }

// ---------------------------------------------------------------------------
// init: blocks 0..3 zero bucket counters; blocks 4..35 build W^T bf16 pairs
// (wt[n*128+kp] = {k=2kp lo, k=2kp+1 hi}).
// ---------------------------------------------------------------------------
__global__ __launch_bounds__(256) void init_kernel(const float* __restrict__ W,
                                                   u32* __restrict__ wt,
                                                   int* __restrict__ bktcnt) {
  if (blockIdx.x < 4) {
    const int i = blockIdx.x * 256 + threadIdx.x;
    if (i < NB) bktcnt[i] = 0;
    return;
  }
  const int g = (blockIdx.x - 4) * 256 + threadIdx.x;  // 0..8191
  const int n = g >> 7;
  const int kp = g & 127;
  const float lo = W[(size_t)(2 * kp) * OUTD + n];
  const float hi = W[(size_t)(2 * kp + 1) * OUTD + n];
  wt[g] = (u32)f2bf(lo) | ((u32)f2bf(hi) << 16);
}

// ---------------------------------------------------------------------------
// GEMM kernel (proven): bf16 MFMA h = x@W, packed bf16 out, s1/s2 epilogue.
// ---------------------------------------------------------------------------
__global__ __launch_bounds__(256) void gemm_kernel(
    const float* __restrict__ x, const u32* __restrict__ wt,
    const float* __restrict__ a, u16* __restrict__ hb,
    float* __restrict__ s1, float* __restrict__ s2)
{
  __shared__ u16 Wl[OUTD * WSTRIDE];  // 33 KB
  const int t = threadIdx.x;
  {  // stage W^T: 2048 uint4 chunks, coalesced global read, padded LDS write
    const uint4* srcv = (const uint4*)wt;
#pragma unroll
    for (int i = 0; i < 8; ++i) {
      const int c = t + 256 * i;
      const int n = c >> 5;
      const int k8 = c & 31;
      *(uint4*)&Wl[n * WSTRIDE + k8 * 8] = srcv[c];
    }
  }
  __syncthreads();

  const int lane = t & 63;
  const int wv = t >> 6;
  const int n = lane & 15;
  const int quad = lane >> 4;
  int rb = blockIdx.x * 64 + wv * 16;
  if (rb > NN - 16) rb = NN - 16;  // tail clamp (dup waves store identical)
  const int row = rb + n;
  const float4* xrow = (const float4*)(x + (size_t)row * DIM);

  floatx4 acc[4] = {{0.f, 0.f, 0.f, 0.f},
                    {0.f, 0.f, 0.f, 0.f},
                    {0.f, 0.f, 0.f, 0.f},
                    {0.f, 0.f, 0.f, 0.f}};

#pragma unroll
  for (int kk = 0; kk < 8; ++kk) {
    const float4 lo = xrow[kk * 8 + quad * 2];
    const float4 hi = xrow[kk * 8 + quad * 2 + 1];
    union { u32 u[4]; short8 s; } af;
    af.u[0] = (u32)f2bf(lo.x) | ((u32)f2bf(lo.y) << 16);
    af.u[1] = (u32)f2bf(lo.z) | ((u32)f2bf(lo.w) << 16);
    af.u[2] = (u32)f2bf(hi.x) | ((u32)f2bf(hi.y) << 16);
    af.u[3] = (u32)f2bf(hi.z) | ((u32)f2bf(hi.w) << 16);
#pragma unroll
    for (int nt = 0; nt < 4; ++nt) {
      const short8 bf =
          *(const short8*)&Wl[(nt * 16 + n) * WSTRIDE + kk * 32 + quad * 8];
      acc[nt] = __builtin_amdgcn_mfma_f32_16x16x32_bf16(af.s, bf, acc[nt], 0, 0, 0);
    }
  }

  float av1[4], av2[4];
#pragma unroll
  for (int nt = 0; nt < 4; ++nt) {
    av1[nt] = a[nt * 16 + n];
    av2[nt] = a[OUTD + nt * 16 + n];
  }

#pragma unroll
  for (int reg = 0; reg < 4; ++reg) {
    const int r = rb + quad * 4 + reg;
    float q1 = acc[0][reg] * av1[0] + acc[1][reg] * av1[1] +
               acc[2][reg] * av1[2] + acc[3][reg] * av1[3];
    float q2 = acc[0][reg] * av2[0] + acc[1][reg] * av2[1] +
               acc[2][reg] * av2[2] + acc[3][reg] * av2[3];
#pragma unroll
    for (int off = 1; off <= 8; off <<= 1) {
      q1 += __shfl_xor(q1, off);
      q2 += __shfl_xor(q2, off);
    }
    if (n == 0) { s1[r] = q1; s2[r] = q2; }
#pragma unroll
    for (int nt = 0; nt < 4; ++nt)
      hb[(size_t)r * OUTD + nt * 16 + n] = f2bf(acc[nt][reg]);
  }
}

// ---------------------------------------------------------------------------
// Bin kernel: chunk-reserved bucket binning, 1024 threads/block (4x the wave
// parallelism per block vs round 7's fused version — per-block serial work
// drops 12 -> 3 iterations per pass). P1=128 keeps 16-edge = 64B exclusive
// chunks (no cross-XCD line bouncing).
// ---------------------------------------------------------------------------
__global__ __launch_bounds__(1024) void bin_kernel(
    const int* __restrict__ src, const int* __restrict__ dst,
    int* __restrict__ bktcnt, u32* __restrict__ binned)
{
  __shared__ int lh[NB];  // 3.1 KB
  const int t = threadIdx.x;
  const int p = blockIdx.x;
  for (int i = t; i < NB; i += 1024) lh[i] = 0;
  __syncthreads();

  const int4* src4 = (const int4*)(src + p * EPB);
  const int4* dst4 = (const int4*)(dst + p * EPB);
  for (int i = t; i < EPB / 4; i += 1024) {
    const int4 s = src4[i];
    if ((u32)s.x < (u32)NN) atomicAdd(&lh[s.x >> BSH], 1);
    if ((u32)s.y < (u32)NN) atomicAdd(&lh[s.y >> BSH], 1);
    if ((u32)s.z < (u32)NN) atomicAdd(&lh[s.z >> BSH], 1);
    if ((u32)s.w < (u32)NN) atomicAdd(&lh[s.w >> BSH], 1);
  }
  __syncthreads();

  // reserve a contiguous chunk per touched bucket; lh becomes the absolute
  // write cursor (b*CAP + base).
  for (int b = t; b < NB; b += 1024) {
    const int c = lh[b];
    lh[b] = (c > 0) ? atomicAdd(bktcnt + b, c) + b * CAP : 0;
  }
  __syncthreads();

  for (int i = t; i < EPB / 4; i += 1024) {
    const int4 s = src4[i];
    const int4 d = dst4[i];
    int pos, b;
    if ((u32)s.x < (u32)NN) {
      b = s.x >> BSH; pos = atomicAdd(&lh[b], 1);
      if (pos < (b + 1) * CAP) binned[pos] = ((u32)(s.x & 63) << 16) | (u32)(d.x & 0xFFFF);
    }
    if ((u32)s.y < (u32)NN) {
      b = s.y >> BSH; pos = atomicAdd(&lh[b], 1);
      if (pos < (b + 1) * CAP) binned[pos] = ((u32)(s.y & 63) << 16) | (u32)(d.y & 0xFFFF);
    }
    if ((u32)s.z < (u32)NN) {
      b = s.z >> BSH; pos = atomicAdd(&lh[b], 1);
      if (pos < (b + 1) * CAP) binned[pos] = ((u32)(s.z & 63) << 16) | (u32)(d.z & 0xFFFF);
    }
    if ((u32)s.w < (u32)NN) {
      b = s.w >> BSH; pos = atomicAdd(&lh[b], 1);
      if (pos < (b + 1) * CAP) binned[pos] = ((u32)(s.w & 63) << 16) | (u32)(d.w & 0xFFFF);
    }
  }
}

// ---------------------------------------------------------------------------
// Group kernel (proven): one block per 64-node bucket. LDS count ->
// wave-0 shuffle scan -> rowstart/deg -> LDS-cursor scatter of u16 dst.
// ---------------------------------------------------------------------------
__global__ __launch_bounds__(256) void group_kernel(
    const u32* __restrict__ binned, const int* __restrict__ bktcnt,
    int* __restrict__ rowstart, int* __restrict__ deg,
    u16* __restrict__ edst16)
{
  __shared__ int cnt[64];
  __shared__ int off[64];
  const int b = blockIdx.x;
  const int t = threadIdx.x;
  int n = bktcnt[b];
  if (n > CAP) n = CAP;
  if (t < 64) cnt[t] = 0;
  __syncthreads();

  const u32* eb = binned + (size_t)b * CAP;
  for (int i = t; i < n; i += 256)
    atomicAdd(&cnt[(eb[i] >> 16) & 63], 1);
  __syncthreads();

  if (t < 64) {  // wave 0: inclusive shuffle scan over 64 counters
    const int v = cnt[t];
    int xx = v;
#pragma unroll
    for (int o = 1; o < 64; o <<= 1) {
      const int y = __shfl_up(xx, o, 64);
      if (t >= o) xx += y;
    }
    off[t] = xx - v;  // exclusive prefix (bucket-local)
    const int node = b * 64 + t;
    if (node < NN) {
      rowstart[node] = b * CAP + xx - v;
      deg[node] = v;
    }
  }
  __syncthreads();

  for (int i = t; i < n; i += 256) {
    const u32 pv = eb[i];
    const int pos = atomicAdd(&off[(pv >> 16) & 63], 1);
    edst16[(size_t)b * CAP + pos] = (u16)(pv & 0xFFFFu);
  }
}

// ---------------------------------------------------------------------------
// Aggregation (proven): one wave per node, register accumulators, 8 edges
// per inner iteration; edst is u16.
// ---------------------------------------------------------------------------
__global__ __launch_bounds__(256) void agg_kernel(
    const u16* __restrict__ hb, const float* __restrict__ s1,
    const float* __restrict__ s2, const int* __restrict__ pre,
    const int* __restrict__ deg, const u16* __restrict__ edst,
    float* __restrict__ out)
{
  const int lane = threadIdx.x & 63;
  const int g = lane >> 3;
  const int seg = lane & 7;
  const int node =
      __builtin_amdgcn_readfirstlane(blockIdx.x * 4 + (threadIdx.x >> 6));
  const int base = pre[node];
  const int cnt = deg[node];
  const float s1i = s1[node];

  float a0 = 0.f, a1 = 0.f, a2 = 0.f, a3 = 0.f;
  float a4 = 0.f, a5 = 0.f, a6 = 0.f, a7 = 0.f;
  float wsum = 0.f;

  for (int c0 = 0; c0 < cnt; c0 += 64) {
    const int m = min(64, cnt - c0);
    int d = 0;
    float w = 0.f;
    if (lane < m) {
      d = edst[(size_t)base + c0 + lane];
      const float logit = s1i + s2[d];
      const float lr = logit > 0.f ? logit : ALPHA * logit;
      w = __expf(-lr);
    }
#pragma unroll 4
    for (int e = 0; e < m; e += 8) {
      const int idx = e + g;
      const int dg = __shfl(d, idx);
      const float wg = __shfl(w, idx);
      const uint4 p = *(const uint4*)(hb + (size_t)dg * OUTD + seg * 8);
      a0 = fmaf(wg, bflo(p.x), a0);
      a1 = fmaf(wg, bfhi(p.x), a1);
      a2 = fmaf(wg, bflo(p.y), a2);
      a3 = fmaf(wg, bfhi(p.y), a3);
      a4 = fmaf(wg, bflo(p.z), a4);
      a5 = fmaf(wg, bfhi(p.z), a5);
      a6 = fmaf(wg, bflo(p.w), a6);
      a7 = fmaf(wg, bfhi(p.w), a7);
      wsum += wg;
    }
  }

#pragma unroll
  for (int off = 8; off <= 32; off <<= 1) {
    a0 += __shfl_xor(a0, off);
    a1 += __shfl_xor(a1, off);
    a2 += __shfl_xor(a2, off);
    a3 += __shfl_xor(a3, off);
    a4 += __shfl_xor(a4, off);
    a5 += __shfl_xor(a5, off);
    a6 += __shfl_xor(a6, off);
    a7 += __shfl_xor(a7, off);
    wsum += __shfl_xor(wsum, off);
  }

  if (g == 0) {
    const float inv = (cnt > 0) ? 1.f / wsum : 0.f;
    float4 r;
    float v;
    v = a0 * inv; r.x = v > 0.f ? v : (__expf(v) - 1.f);
    v = a1 * inv; r.y = v > 0.f ? v : (__expf(v) - 1.f);
    v = a2 * inv; r.z = v > 0.f ? v : (__expf(v) - 1.f);
    v = a3 * inv; r.w = v > 0.f ? v : (__expf(v) - 1.f);
    *(float4*)(out + (size_t)node * OUTD + seg * 8) = r;
    v = a4 * inv; r.x = v > 0.f ? v : (__expf(v) - 1.f);
    v = a5 * inv; r.y = v > 0.f ? v : (__expf(v) - 1.f);
    v = a6 * inv; r.z = v > 0.f ? v : (__expf(v) - 1.f);
    v = a7 * inv; r.w = v > 0.f ? v : (__expf(v) - 1.f);
    *(float4*)(out + (size_t)node * OUTD + seg * 8 + 4) = r;
  }
}

// ---------------------------------------------------------------------------
extern "C" void kernel_launch(void* const* d_in, const int* in_sizes, int n_in,
                              void* d_out, int out_size, void* d_ws, size_t ws_size,
                              hipStream_t stream) {
  const float* x = (const float*)d_in[0];
  const int* ei = (const int*)d_in[1];
  const float* W = (const float*)d_in[2];
  const float* a = (const float*)d_in[3];
  float* out = (float*)d_out;

  // workspace layout (~22 MB)
  u16* hb = (u16*)d_ws;                          // NN*64 bf16 (6.4 MB)
  float* s1 = (float*)(hb + (size_t)NN * OUTD);  // NN
  float* s2 = s1 + NN;                           // NN
  int* rowstart = (int*)(s2 + NN);               // NN
  int* deg = rowstart + NN;                      // NN
  int* bktcnt = deg + NN;                        // NB
  u32* wt = (u32*)(bktcnt + NB);                 // 8192 (32 KB W^T bf16)
  u32* binned = wt + 8192;                       // NB*CAP u32 (9.6 MB)
  u16* edst16 = (u16*)(binned + (size_t)NB * CAP);  // NB*CAP u16 (4.8 MB)

  const int* src = ei;
  const int* dst = ei + NE;

  hipLaunchKernelGGL(init_kernel, dim3(36), dim3(256), 0, stream, W, wt, bktcnt);
  hipLaunchKernelGGL(gemm_kernel, dim3(GEMM_BLOCKS), dim3(256), 0, stream,
                     x, wt, a, hb, s1, s2);
  hipLaunchKernelGGL(bin_kernel, dim3(P1), dim3(1024), 0, stream,
                     src, dst, bktcnt, binned);
  hipLaunchKernelGGL(group_kernel, dim3(NB), dim3(256), 0, stream,
                     binned, bktcnt, rowstart, deg, edst16);
  hipLaunchKernelGGL(agg_kernel, dim3(NN / 4), dim3(256), 0, stream,
                     hb, s1, s2, rowstart, deg, edst16, out);
}

// Round 9
// 163.222 us; speedup vs baseline: 1.0314x; 1.0314x over previous
//
#include <hip/hip_runtime.h>

#define NN 50000
#define NE 1600000
#define DIM 256
#define OUTD 64
#define ALPHA 0.2f

#define BSH 6                  // bucket = src >> 6 (64 nodes/bucket)
#define NB ((NN + 63) >> 6)    // 782 buckets
#define CAP 3072               // per-bucket capacity (mean 2048, sigma ~45)
#define P1 128                 // binning blocks (16-edge = 64B chunks, exclusive lines)
#define EPB (NE / P1)          // 12500 edges per block (div by 4)

#define GEMM_BLOCKS ((NN + 63) / 64)  // 782 (64 rows/block = 16 rows x 4 waves)
#define WSTRIDE 264            // Wl LDS row stride in u16 (256 + 8 pad)

typedef unsigned short u16;
typedef unsigned int u32;
typedef __attribute__((ext_vector_type(8))) short short8;   // 8 bf16 MFMA frag
typedef __attribute__((ext_vector_type(4))) float floatx4;  // MFMA accum

__device__ __forceinline__ u16 f2bf(float f) {
  u32 b = __float_as_uint(f);
  b += 0x7FFFu + ((b >> 16) & 1u);  // RNE
  return (u16)(b >> 16);
}
__device__ __forceinline__ float bflo(u32 u) { return __uint_as_float(u << 16); }
__device__ __forceinline__ float bfhi(u32 u) { return __uint_as_float(u & 0xFFFF0000u); }

// ---------------------------------------------------------------------------
// init: blocks 0..3 zero bucket counters; blocks 4..35 build W^T bf16 pairs
// (wt[n*128+kp] = {k=2kp lo, k=2kp+1 hi}).
// ---------------------------------------------------------------------------
__global__ __launch_bounds__(256) void init_kernel(const float* __restrict__ W,
                                                   u32* __restrict__ wt,
                                                   int* __restrict__ bktcnt) {
  if (blockIdx.x < 4) {
    const int i = blockIdx.x * 256 + threadIdx.x;
    if (i < NB) bktcnt[i] = 0;
    return;
  }
  const int g = (blockIdx.x - 4) * 256 + threadIdx.x;  // 0..8191
  const int n = g >> 7;
  const int kp = g & 127;
  const float lo = W[(size_t)(2 * kp) * OUTD + n];
  const float hi = W[(size_t)(2 * kp + 1) * OUTD + n];
  wt[g] = (u32)f2bf(lo) | ((u32)f2bf(hi) << 16);
}

// ---------------------------------------------------------------------------
// GEMM kernel (proven): bf16 MFMA h = x@W, packed bf16 out, s1/s2 epilogue.
// ---------------------------------------------------------------------------
__global__ __launch_bounds__(256) void gemm_kernel(
    const float* __restrict__ x, const u32* __restrict__ wt,
    const float* __restrict__ a, u16* __restrict__ hb,
    float* __restrict__ s1, float* __restrict__ s2)
{
  __shared__ u16 Wl[OUTD * WSTRIDE];  // 33 KB
  const int t = threadIdx.x;
  {  // stage W^T: 2048 uint4 chunks, coalesced global read, padded LDS write
    const uint4* srcv = (const uint4*)wt;
#pragma unroll
    for (int i = 0; i < 8; ++i) {
      const int c = t + 256 * i;
      const int n = c >> 5;
      const int k8 = c & 31;
      *(uint4*)&Wl[n * WSTRIDE + k8 * 8] = srcv[c];
    }
  }
  __syncthreads();

  const int lane = t & 63;
  const int wv = t >> 6;
  const int n = lane & 15;
  const int quad = lane >> 4;
  int rb = blockIdx.x * 64 + wv * 16;
  if (rb > NN - 16) rb = NN - 16;  // tail clamp (dup waves store identical)
  const int row = rb + n;
  const float4* xrow = (const float4*)(x + (size_t)row * DIM);

  floatx4 acc[4] = {{0.f, 0.f, 0.f, 0.f},
                    {0.f, 0.f, 0.f, 0.f},
                    {0.f, 0.f, 0.f, 0.f},
                    {0.f, 0.f, 0.f, 0.f}};

#pragma unroll
  for (int kk = 0; kk < 8; ++kk) {
    const float4 lo = xrow[kk * 8 + quad * 2];
    const float4 hi = xrow[kk * 8 + quad * 2 + 1];
    union { u32 u[4]; short8 s; } af;
    af.u[0] = (u32)f2bf(lo.x) | ((u32)f2bf(lo.y) << 16);
    af.u[1] = (u32)f2bf(lo.z) | ((u32)f2bf(lo.w) << 16);
    af.u[2] = (u32)f2bf(hi.x) | ((u32)f2bf(hi.y) << 16);
    af.u[3] = (u32)f2bf(hi.z) | ((u32)f2bf(hi.w) << 16);
#pragma unroll
    for (int nt = 0; nt < 4; ++nt) {
      const short8 bf =
          *(const short8*)&Wl[(nt * 16 + n) * WSTRIDE + kk * 32 + quad * 8];
      acc[nt] = __builtin_amdgcn_mfma_f32_16x16x32_bf16(af.s, bf, acc[nt], 0, 0, 0);
    }
  }

  float av1[4], av2[4];
#pragma unroll
  for (int nt = 0; nt < 4; ++nt) {
    av1[nt] = a[nt * 16 + n];
    av2[nt] = a[OUTD + nt * 16 + n];
  }

#pragma unroll
  for (int reg = 0; reg < 4; ++reg) {
    const int r = rb + quad * 4 + reg;
    float q1 = acc[0][reg] * av1[0] + acc[1][reg] * av1[1] +
               acc[2][reg] * av1[2] + acc[3][reg] * av1[3];
    float q2 = acc[0][reg] * av2[0] + acc[1][reg] * av2[1] +
               acc[2][reg] * av2[2] + acc[3][reg] * av2[3];
#pragma unroll
    for (int off = 1; off <= 8; off <<= 1) {
      q1 += __shfl_xor(q1, off);
      q2 += __shfl_xor(q2, off);
    }
    if (n == 0) { s1[r] = q1; s2[r] = q2; }
#pragma unroll
    for (int nt = 0; nt < 4; ++nt)
      hb[(size_t)r * OUTD + nt * 16 + n] = f2bf(acc[nt][reg]);
  }
}

// ---------------------------------------------------------------------------
// Bin kernel (proven round 8): chunk-reserved bucket binning, 1024 thr/block.
// P1=128 keeps 16-edge = 64B exclusive chunks (no cross-XCD line bouncing).
// ---------------------------------------------------------------------------
__global__ __launch_bounds__(1024) void bin_kernel(
    const int* __restrict__ src, const int* __restrict__ dst,
    int* __restrict__ bktcnt, u32* __restrict__ binned)
{
  __shared__ int lh[NB];  // 3.1 KB
  const int t = threadIdx.x;
  const int p = blockIdx.x;
  for (int i = t; i < NB; i += 1024) lh[i] = 0;
  __syncthreads();

  const int4* src4 = (const int4*)(src + p * EPB);
  const int4* dst4 = (const int4*)(dst + p * EPB);
  for (int i = t; i < EPB / 4; i += 1024) {
    const int4 s = src4[i];
    if ((u32)s.x < (u32)NN) atomicAdd(&lh[s.x >> BSH], 1);
    if ((u32)s.y < (u32)NN) atomicAdd(&lh[s.y >> BSH], 1);
    if ((u32)s.z < (u32)NN) atomicAdd(&lh[s.z >> BSH], 1);
    if ((u32)s.w < (u32)NN) atomicAdd(&lh[s.w >> BSH], 1);
  }
  __syncthreads();

  // reserve a contiguous chunk per touched bucket; lh becomes the absolute
  // write cursor (b*CAP + base).
  for (int b = t; b < NB; b += 1024) {
    const int c = lh[b];
    lh[b] = (c > 0) ? atomicAdd(bktcnt + b, c) + b * CAP : 0;
  }
  __syncthreads();

  for (int i = t; i < EPB / 4; i += 1024) {
    const int4 s = src4[i];
    const int4 d = dst4[i];
    int pos, b;
    if ((u32)s.x < (u32)NN) {
      b = s.x >> BSH; pos = atomicAdd(&lh[b], 1);
      if (pos < (b + 1) * CAP) binned[pos] = ((u32)(s.x & 63) << 16) | (u32)(d.x & 0xFFFF);
    }
    if ((u32)s.y < (u32)NN) {
      b = s.y >> BSH; pos = atomicAdd(&lh[b], 1);
      if (pos < (b + 1) * CAP) binned[pos] = ((u32)(s.y & 63) << 16) | (u32)(d.y & 0xFFFF);
    }
    if ((u32)s.z < (u32)NN) {
      b = s.z >> BSH; pos = atomicAdd(&lh[b], 1);
      if (pos < (b + 1) * CAP) binned[pos] = ((u32)(s.z & 63) << 16) | (u32)(d.z & 0xFFFF);
    }
    if ((u32)s.w < (u32)NN) {
      b = s.w >> BSH; pos = atomicAdd(&lh[b], 1);
      if (pos < (b + 1) * CAP) binned[pos] = ((u32)(s.w & 63) << 16) | (u32)(d.w & 0xFFFF);
    }
  }
}

// ---------------------------------------------------------------------------
// Fused group+agg: one 512-thread block per 64-node bucket.
// Phase 1 (group, proven logic): stage bucket edges in LDS, count per local
//   node, wave-0 shuffle scan, scatter into LDS-sorted runs; the edge weight
//   exp(-leakyrelu(s1+s2)) is fused into the scatter pass (computed once).
// Phase 2 (agg, proven inner loop): 8 waves x 8 nodes; per 8-edge iteration
//   (d, w) come from LDS same-address broadcast (replaces shuffle bcast);
//   register accumulators; shuffle reduce; ELU epilogue.
// Deletes the group dispatch and all edst16/rowstart/deg HBM traffic.
// LDS 31 KB -> 4 blocks/CU x 8 waves = 32 waves/CU (max occupancy).
// ---------------------------------------------------------------------------
__global__ __launch_bounds__(512) void bucket_agg_kernel(
    const u16* __restrict__ hb, const float* __restrict__ s1,
    const float* __restrict__ s2, const int* __restrict__ bktcnt,
    const u32* __restrict__ binned, float* __restrict__ out)
{
  __shared__ u32 ebuf[CAP];    // 12 KB staged bucket edges
  __shared__ u16 sdst[CAP];    // 6 KB sorted dst
  __shared__ float wls[CAP];   // 12 KB sorted edge weights
  __shared__ float s1l[64];
  __shared__ int cnt[64];
  __shared__ int off0[64];
  __shared__ int cur[64];
  const int b = blockIdx.x;
  const int t = threadIdx.x;
  int n = bktcnt[b];
  if (n > CAP) n = CAP;

  if (t < 64) {
    cnt[t] = 0;
    const int nd = b * 64 + t;
    s1l[t] = (nd < NN) ? s1[nd] : 0.f;
  }
  __syncthreads();

  const u32* eb = binned + (size_t)b * CAP;
  for (int i = t; i < n; i += 512) {
    const u32 v = eb[i];
    ebuf[i] = v;
    atomicAdd(&cnt[(v >> 16) & 63], 1);
  }
  __syncthreads();

  if (t < 64) {  // wave 0: inclusive shuffle scan over 64 counters
    const int v = cnt[t];
    int xx = v;
#pragma unroll
    for (int o = 1; o < 64; o <<= 1) {
      const int y = __shfl_up(xx, o, 64);
      if (t >= o) xx += y;
    }
    off0[t] = xx - v;  // exclusive prefix (preserved for agg)
    cur[t] = xx - v;   // scatter cursor
  }
  __syncthreads();

  for (int i = t; i < n; i += 512) {
    const u32 v = ebuf[i];
    const int ln = (v >> 16) & 63;
    const int d = (int)(v & 0xFFFFu);
    const int pos = atomicAdd(&cur[ln], 1);
    sdst[pos] = (u16)d;
    const float logit = s1l[ln] + s2[d];
    const float lr = logit > 0.f ? logit : ALPHA * logit;
    wls[pos] = __expf(-lr);
  }
  __syncthreads();

  // ---- agg phase: wave wv handles local nodes wv*8 .. wv*8+7 ----
  const int lane = t & 63;
  const int wv = t >> 6;       // 0..7
  const int g = lane >> 3;     // 8 edge-groups
  const int seg = lane & 7;    // 8 col-segments of 8

  for (int ni = 0; ni < 8; ++ni) {
    const int ln = wv * 8 + ni;
    const int node = b * 64 + ln;
    if (node >= NN) continue;  // wave-uniform (last bucket only)
    const int base = off0[ln];
    const int cend = base + cnt[ln];

    float a0 = 0.f, a1 = 0.f, a2 = 0.f, a3 = 0.f;
    float a4 = 0.f, a5 = 0.f, a6 = 0.f, a7 = 0.f;
    float wsum = 0.f;

    for (int e = base + g; e < cend; e += 8) {
      const int dg = sdst[e];        // same addr for 8 lanes -> LDS broadcast
      const float wg = wls[e];
      const uint4 p = *(const uint4*)(hb + (size_t)dg * OUTD + seg * 8);
      a0 = fmaf(wg, bflo(p.x), a0);
      a1 = fmaf(wg, bfhi(p.x), a1);
      a2 = fmaf(wg, bflo(p.y), a2);
      a3 = fmaf(wg, bfhi(p.y), a3);
      a4 = fmaf(wg, bflo(p.z), a4);
      a5 = fmaf(wg, bfhi(p.z), a5);
      a6 = fmaf(wg, bflo(p.w), a6);
      a7 = fmaf(wg, bfhi(p.w), a7);
      wsum += wg;
    }

#pragma unroll
    for (int off = 8; off <= 32; off <<= 1) {
      a0 += __shfl_xor(a0, off);
      a1 += __shfl_xor(a1, off);
      a2 += __shfl_xor(a2, off);
      a3 += __shfl_xor(a3, off);
      a4 += __shfl_xor(a4, off);
      a5 += __shfl_xor(a5, off);
      a6 += __shfl_xor(a6, off);
      a7 += __shfl_xor(a7, off);
      wsum += __shfl_xor(wsum, off);
    }

    if (g == 0) {
      const float inv = (cnt[ln] > 0) ? 1.f / wsum : 0.f;
      float4 r;
      float v;
      v = a0 * inv; r.x = v > 0.f ? v : (__expf(v) - 1.f);
      v = a1 * inv; r.y = v > 0.f ? v : (__expf(v) - 1.f);
      v = a2 * inv; r.z = v > 0.f ? v : (__expf(v) - 1.f);
      v = a3 * inv; r.w = v > 0.f ? v : (__expf(v) - 1.f);
      *(float4*)(out + (size_t)node * OUTD + seg * 8) = r;
      v = a4 * inv; r.x = v > 0.f ? v : (__expf(v) - 1.f);
      v = a5 * inv; r.y = v > 0.f ? v : (__expf(v) - 1.f);
      v = a6 * inv; r.z = v > 0.f ? v : (__expf(v) - 1.f);
      v = a7 * inv; r.w = v > 0.f ? v : (__expf(v) - 1.f);
      *(float4*)(out + (size_t)node * OUTD + seg * 8 + 4) = r;
    }
  }
}

// ---------------------------------------------------------------------------
extern "C" void kernel_launch(void* const* d_in, const int* in_sizes, int n_in,
                              void* d_out, int out_size, void* d_ws, size_t ws_size,
                              hipStream_t stream) {
  const float* x = (const float*)d_in[0];
  const int* ei = (const int*)d_in[1];
  const float* W = (const float*)d_in[2];
  const float* a = (const float*)d_in[3];
  float* out = (float*)d_out;

  // workspace layout (~17 MB)
  u16* hb = (u16*)d_ws;                          // NN*64 bf16 (6.4 MB)
  float* s1 = (float*)(hb + (size_t)NN * OUTD);  // NN
  float* s2 = s1 + NN;                           // NN
  int* bktcnt = (int*)(s2 + NN);                 // NB
  u32* wt = (u32*)(bktcnt + NB);                 // 8192 (32 KB W^T bf16)
  u32* binned = wt + 8192;                       // NB*CAP u32 (9.6 MB)

  const int* src = ei;
  const int* dst = ei + NE;

  hipLaunchKernelGGL(init_kernel, dim3(36), dim3(256), 0, stream, W, wt, bktcnt);
  hipLaunchKernelGGL(gemm_kernel, dim3(GEMM_BLOCKS), dim3(256), 0, stream,
                     x, wt, a, hb, s1, s2);
  hipLaunchKernelGGL(bin_kernel, dim3(P1), dim3(1024), 0, stream,
                     src, dst, bktcnt, binned);
  hipLaunchKernelGGL(bucket_agg_kernel, dim3(NB), dim3(512), 0, stream,
                     hb, s1, s2, bktcnt, binned, out);
}